// Round 5
// baseline (250.411 us; speedup 1.0000x reference)
//
#include <hip/hip_runtime.h>
#include <stdint.h>

typedef unsigned short u16;
typedef __bf16 bf16x8 __attribute__((ext_vector_type(8)));
typedef float f32x4 __attribute__((ext_vector_type(4)));

#define M_ROWS 16384
#define K_DIM  1568
#define H_DIM  128
#define MT     32              // batch rows per block
#define BK     32
#define NITER  49              // K_DIM / BK
#define PSTR   132             // P row stride in f32 (128 + 4 pad)
#define SCALE  0.02525381361380526f   // 1/sqrt(1568)
#define LOG2E  1.4426950408889634f

__device__ __forceinline__ u16 f32_to_bf16_rne(float f) {
    uint32_t u = __float_as_uint(f);
    uint32_t r = (u + 0x7FFFu + ((u >> 16) & 1u)) >> 16;
    return (u16)r;
}

#define MFMA(a, b, c) __builtin_amdgcn_mfma_f32_16x16x32_bf16(a, b, c, 0, 0, 0)

// ---------------------------------------------------------------------------
// Kernel 1: x [M,K] f32 -> xb [M,K] bf16 (8 elems/thread, fully coalesced)
// ---------------------------------------------------------------------------
__global__ __launch_bounds__(256) void xconv_kernel(
    const float* __restrict__ x, u16* __restrict__ xb)
{
    size_t i = ((size_t)blockIdx.x * 256 + threadIdx.x) * 8;
    float4 f0 = *(const float4*)(x + i);
    float4 f1 = *(const float4*)(x + i + 4);
    union { u16 h[8]; uint4 v; } p;
    p.h[0] = f32_to_bf16_rne(f0.x); p.h[1] = f32_to_bf16_rne(f0.y);
    p.h[2] = f32_to_bf16_rne(f0.z); p.h[3] = f32_to_bf16_rne(f0.w);
    p.h[4] = f32_to_bf16_rne(f1.x); p.h[5] = f32_to_bf16_rne(f1.y);
    p.h[6] = f32_to_bf16_rne(f1.z); p.h[7] = f32_to_bf16_rne(f1.w);
    *(uint4*)(xb + i) = p.v;
}

// ---------------------------------------------------------------------------
// Kernel 2: coalesced transpose + bf16 convert: [K,H] f32 -> WT[3][H][K] bf16
// ---------------------------------------------------------------------------
__global__ __launch_bounds__(256) void wtrans_kernel(
    const float* __restrict__ wq, const float* __restrict__ wk,
    const float* __restrict__ wv, u16* __restrict__ wt)
{
    __shared__ u16 tile[32][33];
    const float* w = (blockIdx.z == 0) ? wq : (blockIdx.z == 1) ? wk : wv;
    const int k0 = blockIdx.x * 32;
    const int n0 = blockIdx.y * 32;

    const int tn = threadIdx.x & 31;
    const int tk = threadIdx.x >> 5;
    #pragma unroll
    for (int p = 0; p < 4; p++) {
        int kk = tk + p * 8;
        tile[kk][tn] = f32_to_bf16_rne(w[(size_t)(k0 + kk) * H_DIM + n0 + tn]);
    }
    __syncthreads();

    u16* dst = wt + (size_t)blockIdx.z * H_DIM * K_DIM;
    const int tk2 = threadIdx.x & 31;
    const int tn2 = threadIdx.x >> 5;
    #pragma unroll
    for (int p = 0; p < 4; p++) {
        int nn = tn2 + p * 8;
        dst[(size_t)(n0 + nn) * K_DIM + k0 + tk2] = tile[tk2][nn];
    }
}

// ---------------------------------------------------------------------------
// Kernel 3 (fused): 512 threads = 8 waves, 32 batch rows per block.
// GEMM phase: BARRIER-FREE. All fragments loaded straight from global into
// registers (A from bf16 x, B from transposed bf16 weights, L2-resident).
// Wave w owns n-range [w*48, w*48+48): 2 m-tiles x 3 n-tiles = 6 MFMA/iter.
// Depth-1 prefetch; #pragma unroll 2 renames the register copies away.
// Attention phase: rank-1 softmax (no max-sub needed; scores bounded).
// ---------------------------------------------------------------------------
__global__ __launch_bounds__(512) void fused_kernel(
    const u16* __restrict__ xb,      // [M,K] bf16
    const u16* __restrict__ wt,      // [3][H][K] bf16
    float* __restrict__ out)         // [M,H] fp32
{
    __shared__ float Pq[MT][PSTR];   // q * SCALE * LOG2E
    __shared__ float Pk[MT][PSTR];
    __shared__ float Pv[MT][PSTR];

    const int tid  = threadIdx.x;
    const int lane = tid & 63;
    const int wave = tid >> 6;
    const int lrow = lane & 15;
    const int quad = lane >> 4;
    const int m0   = blockIdx.x * MT;

    // ---- fragment base pointers ----
    const u16* ap0 = xb + (size_t)(m0 + lrow) * K_DIM + quad * 8;
    const u16* ap1 = ap0 + (size_t)16 * K_DIM;
    const u16* bp[3];
    #pragma unroll
    for (int nt = 0; nt < 3; nt++) {
        int ng = wave * 48 + nt * 16 + lrow;
        bp[nt] = wt + (size_t)(ng >> 7) * (H_DIM * K_DIM)
                    + (size_t)(ng & 127) * K_DIM + quad * 8;
    }

    f32x4 acc[2][3] = {};

    // ---- prologue: fragments for k=0 ----
    bf16x8 a0 = *(const bf16x8*)(ap0);
    bf16x8 a1 = *(const bf16x8*)(ap1);
    bf16x8 b0 = *(const bf16x8*)(bp[0]);
    bf16x8 b1 = *(const bf16x8*)(bp[1]);
    bf16x8 b2 = *(const bf16x8*)(bp[2]);

    #pragma unroll 2
    for (int kk = 1; kk < NITER; kk++) {
        const int ko = kk * BK;
        // prefetch next iteration (pure dataflow, no barrier)
        bf16x8 an0 = *(const bf16x8*)(ap0 + ko);
        bf16x8 an1 = *(const bf16x8*)(ap1 + ko);
        bf16x8 bn0 = *(const bf16x8*)(bp[0] + ko);
        bf16x8 bn1 = *(const bf16x8*)(bp[1] + ko);
        bf16x8 bn2 = *(const bf16x8*)(bp[2] + ko);

        acc[0][0] = MFMA(a0, b0, acc[0][0]);
        acc[1][0] = MFMA(a1, b0, acc[1][0]);
        acc[0][1] = MFMA(a0, b1, acc[0][1]);
        acc[1][1] = MFMA(a1, b1, acc[1][1]);
        acc[0][2] = MFMA(a0, b2, acc[0][2]);
        acc[1][2] = MFMA(a1, b2, acc[1][2]);

        a0 = an0; a1 = an1; b0 = bn0; b1 = bn1; b2 = bn2;
    }
    acc[0][0] = MFMA(a0, b0, acc[0][0]);
    acc[1][0] = MFMA(a1, b0, acc[1][0]);
    acc[0][1] = MFMA(a0, b1, acc[0][1]);
    acc[1][1] = MFMA(a1, b1, acc[1][1]);
    acc[0][2] = MFMA(a0, b2, acc[0][2]);
    acc[1][2] = MFMA(a1, b2, acc[1][2]);

    // ---- scatter projections to LDS (D: row = quad*4+r, col = lane&15) ----
    #pragma unroll
    for (int mt = 0; mt < 2; mt++) {
        #pragma unroll
        for (int nt = 0; nt < 3; nt++) {
            const int base = wave * 48 + nt * 16;    // tile never straddles heads
            const int sel  = base >> 7;
            const int col  = (base & 127) + lrow;
            const int mrow = mt * 16 + quad * 4;
            if (sel == 0) {
                #pragma unroll
                for (int r = 0; r < 4; r++)
                    Pq[mrow + r][col] = acc[mt][nt][r] * (SCALE * LOG2E);
            } else if (sel == 1) {
                #pragma unroll
                for (int r = 0; r < 4; r++)
                    Pk[mrow + r][col] = acc[mt][nt][r];
            } else {
                #pragma unroll
                for (int r = 0; r < 4; r++)
                    Pv[mrow + r][col] = acc[mt][nt][r];
            }
        }
    }
    __syncthreads();

    // ---- attention: r = row (32), sub (16) x 8 outputs each ----
    const int r   = tid >> 4;
    const int sub = tid & 15;

    float qq[8], num[8], den[8];
    #pragma unroll
    for (int ii = 0; ii < 8; ii++) {
        qq[ii]  = Pq[r][sub * 8 + ii];
        num[ii] = 0.f;
        den[ii] = 0.f;
    }

    #pragma unroll 4
    for (int j = 0; j < 128; j++) {
        float kj = Pk[r][j];
        float vj = Pv[r][j];
        #pragma unroll
        for (int ii = 0; ii < 8; ii++) {
            float e = __builtin_amdgcn_exp2f(qq[ii] * kj);
            den[ii] += e;
            num[ii] += e * vj;
        }
    }

    float* op = out + (size_t)(m0 + r) * H_DIM + sub * 8;
    #pragma unroll
    for (int g = 0; g < 2; g++) {
        float4 o;
        o.x = num[4 * g + 0] / den[4 * g + 0];
        o.y = num[4 * g + 1] / den[4 * g + 1];
        o.z = num[4 * g + 2] / den[4 * g + 2];
        o.w = num[4 * g + 3] / den[4 * g + 3];
        *(float4*)(op + 4 * g) = o;
    }
}

// ---------------------------------------------------------------------------
extern "C" void kernel_launch(void* const* d_in, const int* in_sizes, int n_in,
                              void* d_out, int out_size, void* d_ws, size_t ws_size,
                              hipStream_t stream)
{
    const float* x  = (const float*)d_in[0];
    const float* wq = (const float*)d_in[1];
    const float* wk = (const float*)d_in[2];
    const float* wv = (const float*)d_in[3];
    float* out = (float*)d_out;

    // ws layout: wt [3][128][1568] bf16 (1.2 MB), then xb [16384][1568] bf16 (51.4 MB)
    u16* wt = (u16*)d_ws;
    u16* xb = (u16*)((char*)d_ws + (size_t)3 * H_DIM * K_DIM * 2);

    wtrans_kernel<<<dim3(K_DIM / 32, H_DIM / 32, 3), 256, 0, stream>>>(wq, wk, wv, wt);
    xconv_kernel<<<(M_ROWS * K_DIM) / (8 * 256), 256, 0, stream>>>(x, xb);
    fused_kernel<<<M_ROWS / MT, 512, 0, stream>>>(xb, wt, out);
}

// Round 6
// 222.490 us; speedup vs baseline: 1.1255x; 1.1255x over previous
//
#include <hip/hip_runtime.h>
#include <stdint.h>

typedef unsigned short u16;
typedef __bf16 bf16x8 __attribute__((ext_vector_type(8)));
typedef float f32x4 __attribute__((ext_vector_type(4)));

#define M_ROWS 16384
#define K_DIM  1568
#define H_DIM  128
#define MT     32              // batch rows per block
#define BK     32
#define K0LEN  768             // first staged half (24 iters)
#define K1LEN  800             // second staged half (25 iters)
#define ASTR   808             // A LDS row stride in u16 (800 + 8; 1616 B = 101*16 -> odd 16B groups)
#define PSTR   132             // P row stride in f32 (128 + 4 pad)
#define SCALE  0.02525381361380526f   // 1/sqrt(1568)
#define LOG2E  1.4426950408889634f

__device__ __forceinline__ u16 f32_to_bf16_rne(float f) {
    uint32_t u = __float_as_uint(f);
    uint32_t r = (u + 0x7FFFu + ((u >> 16) & 1u)) >> 16;
    return (u16)r;
}

#define MFMA(a, b, c) __builtin_amdgcn_mfma_f32_16x16x32_bf16(a, b, c, 0, 0, 0)

// ---------------------------------------------------------------------------
// Kernel 1: coalesced transpose + bf16 convert: [K,H] f32 -> WT[3][H][K] bf16
// ---------------------------------------------------------------------------
__global__ __launch_bounds__(256) void wtrans_kernel(
    const float* __restrict__ wq, const float* __restrict__ wk,
    const float* __restrict__ wv, u16* __restrict__ wt)
{
    __shared__ u16 tile[32][33];
    const float* w = (blockIdx.z == 0) ? wq : (blockIdx.z == 1) ? wk : wv;
    const int k0 = blockIdx.x * 32;
    const int n0 = blockIdx.y * 32;

    const int tn = threadIdx.x & 31;
    const int tk = threadIdx.x >> 5;
    #pragma unroll
    for (int p = 0; p < 4; p++) {
        int kk = tk + p * 8;
        tile[kk][tn] = f32_to_bf16_rne(w[(size_t)(k0 + kk) * H_DIM + n0 + tn]);
    }
    __syncthreads();

    u16* dst = wt + (size_t)blockIdx.z * H_DIM * K_DIM;
    const int tk2 = threadIdx.x & 31;
    const int tn2 = threadIdx.x >> 5;
    #pragma unroll
    for (int p = 0; p < 4; p++) {
        int nn = tn2 + p * 8;
        dst[(size_t)(n0 + nn) * K_DIM + k0 + tk2] = tile[tk2][nn];
    }
}

// ---------------------------------------------------------------------------
// Kernel 2 (fused): 512 threads = 8 waves, 32 batch rows per block.
// GEMM: A (x rows, f32) staged f32->bf16 into LDS in two K-halves (5 barriers
// total); inner loop is barrier-free: A from LDS (ds_read_b128), B from
// L2-resident transposed weights with depth-1 register prefetch.
// Attention: rank-1 softmax in LDS (P aliases the A staging buffer).
// ---------------------------------------------------------------------------
__global__ __launch_bounds__(512, 4) void fused_kernel(
    const float* __restrict__ x,     // [M,K] fp32
    const u16* __restrict__ wt,      // [3][H][K] bf16
    float* __restrict__ out)         // [M,H] fp32
{
    // A-stage buffer (32 x 808 u16 = 51712 B) aliased with P (3*32*132 f32 = 50688 B)
    __shared__ char smem[MT * ASTR * 2];
    u16*  Abuf = (u16*)smem;
    float (*Pq)[PSTR] = (float (*)[PSTR])smem;
    float (*Pk)[PSTR] = (float (*)[PSTR])(smem + MT * PSTR * 4);
    float (*Pv)[PSTR] = (float (*)[PSTR])(smem + 2 * MT * PSTR * 4);

    const int tid  = threadIdx.x;
    const int lane = tid & 63;
    const int wave = tid >> 6;
    const int lrow = lane & 15;
    const int quad = lane >> 4;
    const int m0   = blockIdx.x * MT;

    // ---- B fragment pointers (per wave, 3 n-tiles of 16) ----
    const u16* bp[3];
    #pragma unroll
    for (int nt = 0; nt < 3; nt++) {
        int ng = wave * 48 + nt * 16 + lrow;
        bp[nt] = wt + (size_t)(ng >> 7) * (H_DIM * K_DIM)
                    + (size_t)(ng & 127) * K_DIM + quad * 8;
    }

    // ---- staging geometry: 16 threads per row, float4 granules ----
    const int srow = tid >> 4;           // 0..31
    const int st16 = tid & 15;           // 0..15
    const float* xrow = x + (size_t)(m0 + srow) * K_DIM;

    f32x4 acc[2][3] = {};
    const u16* a_ld0 = &Abuf[(0 * 16 + lrow) * ASTR + quad * 8];
    const u16* a_ld1 = &Abuf[(1 * 16 + lrow) * ASTR + quad * 8];

    // ================= stage half 0: k [0, 768) =================
    for (int i = st16; i < K0LEN / 4; i += 16) {
        float4 f = *(const float4*)(xrow + i * 4);
        union { u16 h[4]; uint2 v; } p;
        p.h[0] = f32_to_bf16_rne(f.x); p.h[1] = f32_to_bf16_rne(f.y);
        p.h[2] = f32_to_bf16_rne(f.z); p.h[3] = f32_to_bf16_rne(f.w);
        *(uint2*)&Abuf[srow * ASTR + i * 4] = p.v;
    }
    __syncthreads();

    bf16x8 b0 = *(const bf16x8*)(bp[0]);
    bf16x8 b1 = *(const bf16x8*)(bp[1]);
    bf16x8 b2 = *(const bf16x8*)(bp[2]);

    #pragma unroll 2
    for (int it = 0; it < 24; it++) {
        const int kn = (it + 1) * BK;            // global k of next iter (<=768, valid)
        bf16x8 bn0 = *(const bf16x8*)(bp[0] + kn);
        bf16x8 bn1 = *(const bf16x8*)(bp[1] + kn);
        bf16x8 bn2 = *(const bf16x8*)(bp[2] + kn);

        bf16x8 a0 = *(const bf16x8*)(a_ld0 + it * BK);
        bf16x8 a1 = *(const bf16x8*)(a_ld1 + it * BK);

        acc[0][0] = MFMA(a0, b0, acc[0][0]);
        acc[1][0] = MFMA(a1, b0, acc[1][0]);
        acc[0][1] = MFMA(a0, b1, acc[0][1]);
        acc[1][1] = MFMA(a1, b1, acc[1][1]);
        acc[0][2] = MFMA(a0, b2, acc[0][2]);
        acc[1][2] = MFMA(a1, b2, acc[1][2]);

        b0 = bn0; b1 = bn1; b2 = bn2;
    }
    __syncthreads();

    // ================= stage half 1: k [768, 1568) =================
    for (int i = st16; i < K1LEN / 4; i += 16) {
        float4 f = *(const float4*)(xrow + K0LEN + i * 4);
        union { u16 h[4]; uint2 v; } p;
        p.h[0] = f32_to_bf16_rne(f.x); p.h[1] = f32_to_bf16_rne(f.y);
        p.h[2] = f32_to_bf16_rne(f.z); p.h[3] = f32_to_bf16_rne(f.w);
        *(uint2*)&Abuf[srow * ASTR + i * 4] = p.v;
    }
    __syncthreads();

    #pragma unroll 2
    for (int it = 0; it < 25; it++) {
        int kn = K0LEN + (it + 1) * BK;
        if (kn > K_DIM - BK) kn = K_DIM - BK;    // clamp (last prefetch unused)
        bf16x8 bn0 = *(const bf16x8*)(bp[0] + kn);
        bf16x8 bn1 = *(const bf16x8*)(bp[1] + kn);
        bf16x8 bn2 = *(const bf16x8*)(bp[2] + kn);

        bf16x8 a0 = *(const bf16x8*)(a_ld0 + it * BK);
        bf16x8 a1 = *(const bf16x8*)(a_ld1 + it * BK);

        acc[0][0] = MFMA(a0, b0, acc[0][0]);
        acc[1][0] = MFMA(a1, b0, acc[1][0]);
        acc[0][1] = MFMA(a0, b1, acc[0][1]);
        acc[1][1] = MFMA(a1, b1, acc[1][1]);
        acc[0][2] = MFMA(a0, b2, acc[0][2]);
        acc[1][2] = MFMA(a1, b2, acc[1][2]);

        b0 = bn0; b1 = bn1; b2 = bn2;
    }
    __syncthreads();   // all A reads done before P overwrites the buffer

    // ---- scatter projections to LDS (D: row = quad*4+r, col = lane&15) ----
    #pragma unroll
    for (int mt = 0; mt < 2; mt++) {
        #pragma unroll
        for (int nt = 0; nt < 3; nt++) {
            const int base = wave * 48 + nt * 16;    // tile never straddles heads
            const int sel  = base >> 7;
            const int col  = (base & 127) + lrow;
            const int mrow = mt * 16 + quad * 4;
            if (sel == 0) {
                #pragma unroll
                for (int r = 0; r < 4; r++)
                    Pq[mrow + r][col] = acc[mt][nt][r] * (SCALE * LOG2E);
            } else if (sel == 1) {
                #pragma unroll
                for (int r = 0; r < 4; r++)
                    Pk[mrow + r][col] = acc[mt][nt][r];
            } else {
                #pragma unroll
                for (int r = 0; r < 4; r++)
                    Pv[mrow + r][col] = acc[mt][nt][r];
            }
        }
    }
    __syncthreads();

    // ---- attention: r = row (32), sub (16) x 8 outputs each ----
    const int r   = tid >> 4;
    const int sub = tid & 15;

    float qq[8], num[8], den[8];
    #pragma unroll
    for (int ii = 0; ii < 8; ii++) {
        qq[ii]  = Pq[r][sub * 8 + ii];
        num[ii] = 0.f;
        den[ii] = 0.f;
    }

    #pragma unroll 4
    for (int j = 0; j < 128; j++) {
        float kj = Pk[r][j];
        float vj = Pv[r][j];
        #pragma unroll
        for (int ii = 0; ii < 8; ii++) {
            float e = __builtin_amdgcn_exp2f(qq[ii] * kj);
            den[ii] += e;
            num[ii] += e * vj;
        }
    }

    float* op = out + (size_t)(m0 + r) * H_DIM + sub * 8;
    #pragma unroll
    for (int g = 0; g < 2; g++) {
        float4 o;
        o.x = num[4 * g + 0] / den[4 * g + 0];
        o.y = num[4 * g + 1] / den[4 * g + 1];
        o.z = num[4 * g + 2] / den[4 * g + 2];
        o.w = num[4 * g + 3] / den[4 * g + 3];
        *(float4*)(op + 4 * g) = o;
    }
}

// ---------------------------------------------------------------------------
extern "C" void kernel_launch(void* const* d_in, const int* in_sizes, int n_in,
                              void* d_out, int out_size, void* d_ws, size_t ws_size,
                              hipStream_t stream)
{
    const float* x  = (const float*)d_in[0];
    const float* wq = (const float*)d_in[1];
    const float* wk = (const float*)d_in[2];
    const float* wv = (const float*)d_in[3];
    float* out = (float*)d_out;

    u16* wt = (u16*)d_ws;   // [3][128][1568] bf16 = 1.2 MB

    wtrans_kernel<<<dim3(K_DIM / 32, H_DIM / 32, 3), 256, 0, stream>>>(wq, wk, wv, wt);
    fused_kernel<<<M_ROWS / MT, 512, 0, stream>>>(x, wt, out);
}

// Round 8
// 212.252 us; speedup vs baseline: 1.1798x; 1.0482x over previous
//
#include <hip/hip_runtime.h>
#include <stdint.h>

typedef unsigned short u16;
typedef __bf16 bf16x8 __attribute__((ext_vector_type(8)));
typedef float f32x4 __attribute__((ext_vector_type(4)));

#define M_ROWS 16384
#define K_DIM  1568
#define H_DIM  128
#define NQ     384
#define MT     32              // batch rows per block
#define BK     32
#define NSTEP  49              // K_DIM / BK
#define K0LEN  768             // first staged half (24 iters)
#define K1LEN  800             // second staged half (25 iters)
#define ASTR   808             // A LDS row stride in u16 (2-way bank alias = free)
#define PSTR   132             // P row stride in f32
#define KSTRIDE (NQ * BK)      // wt2 elements per kstep = 12288
#define SCALE  0.02525381361380526f   // 1/sqrt(1568)
#define LOG2E  1.4426950408889634f

__device__ __forceinline__ u16 f32_to_bf16_rne(float f) {
    uint32_t u = __float_as_uint(f);
    uint32_t r = (u + 0x7FFFu + ((u >> 16) & 1u)) >> 16;
    return (u16)r;
}

#define MFMA(a, b, c) __builtin_amdgcn_mfma_f32_16x16x32_bf16(a, b, c, 0, 0, 0)

// ---------------------------------------------------------------------------
// Kernel 1: weights -> fragment-ordered wt2[(kstep*384 + n)*32 + klo] (bf16)
// grid (K/32, 128/32, 3) block 256; LDS 32x32 tile; both sides coalesced.
// n_global = z*128 + y*32 + col.
// ---------------------------------------------------------------------------
__global__ __launch_bounds__(256) void wtrans_kernel(
    const float* __restrict__ wq, const float* __restrict__ wk,
    const float* __restrict__ wv, u16* __restrict__ wt2)
{
    __shared__ u16 tile[32][33];
    const float* w = (blockIdx.z == 0) ? wq : (blockIdx.z == 1) ? wk : wv;
    const int k0 = blockIdx.x * 32;
    const int nloc0 = blockIdx.y * 32;            // within-weight col base
    const int ng0 = blockIdx.z * 128 + nloc0;     // global n base

    const int tn = threadIdx.x & 31;
    const int tk = threadIdx.x >> 5;
    #pragma unroll
    for (int p = 0; p < 4; p++) {
        int kk = tk + p * 8;
        tile[kk][tn] = f32_to_bf16_rne(w[(size_t)(k0 + kk) * H_DIM + nloc0 + tn]);
    }
    __syncthreads();

    const int klo = threadIdx.x & 31;             // consecutive -> coalesced store
    const int tn2 = threadIdx.x >> 5;
    u16* dst = wt2 + (size_t)(k0 >> 5) * KSTRIDE;
    #pragma unroll
    for (int p = 0; p < 4; p++) {
        int nn = tn2 + p * 8;
        dst[(size_t)(ng0 + nn) * 32 + klo] = tile[klo][nn];
    }
}

// ---------------------------------------------------------------------------
// Kernel 2 (fused): 512 threads = 8 waves, 32 batch rows per block.
// A staged f32->bf16 (non-temporal reads) into LDS, two K-halves, 5 barriers.
// B from fragment-ordered wt2: 1KB contiguous per fragment load, depth-2
// register pipeline. Attention: rank-1 softmax; P aliases the A buffer.
// ---------------------------------------------------------------------------
__global__ __launch_bounds__(512) void fused_kernel(
    const float* __restrict__ x,     // [M,K] fp32
    const u16* __restrict__ wt2,     // fragment-ordered weights
    float* __restrict__ out)         // [M,H] fp32
{
    __shared__ char smem[MT * ASTR * 2];
    u16*  Abuf = (u16*)smem;
    float (*Pq)[PSTR] = (float (*)[PSTR])smem;
    float (*Pk)[PSTR] = (float (*)[PSTR])(smem + MT * PSTR * 4);
    float (*Pv)[PSTR] = (float (*)[PSTR])(smem + 2 * MT * PSTR * 4);

    const int tid  = threadIdx.x;
    const int lane = tid & 63;
    const int wave = tid >> 6;
    const int lrow = lane & 15;
    const int quad = lane >> 4;
    const int m0   = blockIdx.x * MT;

    // ---- B fragment pointers: contiguous 16B/lane in wt2 ----
    const u16* bp[3];
    #pragma unroll
    for (int nt = 0; nt < 3; nt++) {
        int ng = wave * 48 + nt * 16 + lrow;
        bp[nt] = wt2 + (size_t)ng * 32 + quad * 8;
    }

    // ---- staging geometry: 16 threads per row, float4 granules, NT loads ----
    const int srow = tid >> 4;
    const int st16 = tid & 15;
    const float* xrow = x + (size_t)(m0 + srow) * K_DIM;

    f32x4 acc[2][3] = {};
    const u16* a_ld0 = &Abuf[(0 * 16 + lrow) * ASTR + quad * 8];
    const u16* a_ld1 = &Abuf[(1 * 16 + lrow) * ASTR + quad * 8];

    // ================= stage half 0: k [0, 768) =================
    for (int i = st16; i < K0LEN / 4; i += 16) {
        f32x4 f = __builtin_nontemporal_load((const f32x4*)(xrow + i * 4));
        union { u16 h[4]; uint2 v; } p;
        p.h[0] = f32_to_bf16_rne(f.x); p.h[1] = f32_to_bf16_rne(f.y);
        p.h[2] = f32_to_bf16_rne(f.z); p.h[3] = f32_to_bf16_rne(f.w);
        *(uint2*)&Abuf[srow * ASTR + i * 4] = p.v;
    }

    // ---- B pipeline prologue: ksteps 0 and 1 in flight ----
    bf16x8 B0[3], B1[3];
    #pragma unroll
    for (int nt = 0; nt < 3; nt++) {
        B0[nt] = *(const bf16x8*)(bp[nt]);
        B1[nt] = *(const bf16x8*)(bp[nt] + KSTRIDE);
    }
    __syncthreads();

    #pragma unroll 2
    for (int it = 0; it < 24; it++) {
        const size_t kpf = (size_t)(it + 2) * KSTRIDE;   // it+2 <= 25 < 49: valid
        bf16x8 B2_0 = *(const bf16x8*)(bp[0] + kpf);
        bf16x8 B2_1 = *(const bf16x8*)(bp[1] + kpf);
        bf16x8 B2_2 = *(const bf16x8*)(bp[2] + kpf);

        bf16x8 a0 = *(const bf16x8*)(a_ld0 + it * BK);
        bf16x8 a1 = *(const bf16x8*)(a_ld1 + it * BK);

        acc[0][0] = MFMA(a0, B0[0], acc[0][0]);
        acc[1][0] = MFMA(a1, B0[0], acc[1][0]);
        acc[0][1] = MFMA(a0, B0[1], acc[0][1]);
        acc[1][1] = MFMA(a1, B0[1], acc[1][1]);
        acc[0][2] = MFMA(a0, B0[2], acc[0][2]);
        acc[1][2] = MFMA(a1, B0[2], acc[1][2]);

        B0[0] = B1[0]; B0[1] = B1[1]; B0[2] = B1[2];
        B1[0] = B2_0;  B1[1] = B2_1;  B1[2] = B2_2;
    }
    __syncthreads();

    // ================= stage half 1: k [768, 1568) =================
    for (int i = st16; i < K1LEN / 4; i += 16) {
        f32x4 f = __builtin_nontemporal_load((const f32x4*)(xrow + K0LEN + i * 4));
        union { u16 h[4]; uint2 v; } p;
        p.h[0] = f32_to_bf16_rne(f.x); p.h[1] = f32_to_bf16_rne(f.y);
        p.h[2] = f32_to_bf16_rne(f.z); p.h[3] = f32_to_bf16_rne(f.w);
        *(uint2*)&Abuf[srow * ASTR + i * 4] = p.v;
    }
    __syncthreads();

    #pragma unroll 2
    for (int it = 0; it < 25; it++) {
        int kg = 24 + it + 2;                      // global kstep to prefetch
        if (kg > NSTEP - 1) kg = NSTEP - 1;        // clamp (redundant reload, harmless)
        const size_t kpf = (size_t)kg * KSTRIDE;
        bf16x8 B2_0 = *(const bf16x8*)(bp[0] + kpf);
        bf16x8 B2_1 = *(const bf16x8*)(bp[1] + kpf);
        bf16x8 B2_2 = *(const bf16x8*)(bp[2] + kpf);

        bf16x8 a0 = *(const bf16x8*)(a_ld0 + it * BK);
        bf16x8 a1 = *(const bf16x8*)(a_ld1 + it * BK);

        acc[0][0] = MFMA(a0, B0[0], acc[0][0]);
        acc[1][0] = MFMA(a1, B0[0], acc[1][0]);
        acc[0][1] = MFMA(a0, B0[1], acc[0][1]);
        acc[1][1] = MFMA(a1, B0[1], acc[1][1]);
        acc[0][2] = MFMA(a0, B0[2], acc[0][2]);
        acc[1][2] = MFMA(a1, B0[2], acc[1][2]);

        B0[0] = B1[0]; B0[1] = B1[1]; B0[2] = B1[2];
        B1[0] = B2_0;  B1[1] = B2_1;  B1[2] = B2_2;
    }
    __syncthreads();   // all A reads done before P overwrites the buffer

    // ---- scatter projections to LDS (D: row = quad*4+r, col = lane&15) ----
    #pragma unroll
    for (int mt = 0; mt < 2; mt++) {
        #pragma unroll
        for (int nt = 0; nt < 3; nt++) {
            const int base = wave * 48 + nt * 16;    // tile never straddles heads
            const int sel  = base >> 7;
            const int col  = (base & 127) + lrow;
            const int mrow = mt * 16 + quad * 4;
            if (sel == 0) {
                #pragma unroll
                for (int r = 0; r < 4; r++)
                    Pq[mrow + r][col] = acc[mt][nt][r] * (SCALE * LOG2E);
            } else if (sel == 1) {
                #pragma unroll
                for (int r = 0; r < 4; r++)
                    Pk[mrow + r][col] = acc[mt][nt][r];
            } else {
                #pragma unroll
                for (int r = 0; r < 4; r++)
                    Pv[mrow + r][col] = acc[mt][nt][r];
            }
        }
    }
    __syncthreads();

    // ---- attention: r = row (32), sub (16) x 8 outputs each ----
    const int r   = tid >> 4;
    const int sub = tid & 15;

    float qq[8], num[8], den[8];
    #pragma unroll
    for (int ii = 0; ii < 8; ii++) {
        qq[ii]  = Pq[r][sub * 8 + ii];
        num[ii] = 0.f;
        den[ii] = 0.f;
    }

    #pragma unroll 4
    for (int j = 0; j < 128; j++) {
        float kj = Pk[r][j];
        float vj = Pv[r][j];
        #pragma unroll
        for (int ii = 0; ii < 8; ii++) {
            float e = __builtin_amdgcn_exp2f(qq[ii] * kj);
            den[ii] += e;
            num[ii] += e * vj;
        }
    }

    float* op = out + (size_t)(m0 + r) * H_DIM + sub * 8;
    #pragma unroll
    for (int g = 0; g < 2; g++) {
        f32x4 o;
        o.x = num[4 * g + 0] / den[4 * g + 0];
        o.y = num[4 * g + 1] / den[4 * g + 1];
        o.z = num[4 * g + 2] / den[4 * g + 2];
        o.w = num[4 * g + 3] / den[4 * g + 3];
        __builtin_nontemporal_store(o, (f32x4*)(op + 4 * g));
    }
}

// ---------------------------------------------------------------------------
extern "C" void kernel_launch(void* const* d_in, const int* in_sizes, int n_in,
                              void* d_out, int out_size, void* d_ws, size_t ws_size,
                              hipStream_t stream)
{
    const float* x  = (const float*)d_in[0];
    const float* wq = (const float*)d_in[1];
    const float* wk = (const float*)d_in[2];
    const float* wv = (const float*)d_in[3];
    float* out = (float*)d_out;

    u16* wt2 = (u16*)d_ws;   // 49*384*32 u16 = 1.2 MB

    wtrans_kernel<<<dim3(K_DIM / 32, H_DIM / 32, 3), 256, 0, stream>>>(wq, wk, wv, wt2);
    fused_kernel<<<M_ROWS / MT, 512, 0, stream>>>(x, wt2, out);
}